// Round 6
// baseline (407.851 us; speedup 1.0000x reference)
//
#include <hip/hip_runtime.h>
#include <hip/hip_fp16.h>
#include <hip/hip_cooperative_groups.h>

namespace cg = cooperative_groups;

#define RR 32
#define R3 32768           // 32^3
#define NPTS 65536
#define NCH 64
#define NB 8

// ---------------- fused prep: mean -> maxnorm -> nc/vid/hist (cooperative) ----------------
// grid = 256 blocks x 256 threads; 32 blocks per batch; 8 points per thread.

__global__ void prep_kernel(const float* __restrict__ coords,
                            float* __restrict__ ncout,
                            int* __restrict__ vid,
                            unsigned* __restrict__ cnt,
                            double* __restrict__ part,      // [NB*32*4] doubles
                            float* __restrict__ partmax) {  // [NB*32]
    cg::grid_group grid = cg::this_grid();
    __shared__ double wsum[3][4];
    __shared__ float  wmax[4];
    __shared__ float  bshare[4];   // mx,my,mz,denom

    int blk = blockIdx.x;
    int b   = blk >> 5;
    int sub = blk & 31;
    int t   = threadIdx.x;
    int wave = t >> 6, lane = t & 63;
    const float* cb = coords + (size_t)b * 3 * NPTS;
    int base = sub * 2048 + t;

    // ---- P1: per-block partial sums ----
    double sx = 0.0, sy = 0.0, sz = 0.0;
#pragma unroll
    for (int j = 0; j < 8; j++) {
        int n = base + j * 256;
        sx += cb[n];
        sy += cb[NPTS + n];
        sz += cb[2 * NPTS + n];
    }
    for (int off = 32; off > 0; off >>= 1) {
        sx += __shfl_down(sx, off);
        sy += __shfl_down(sy, off);
        sz += __shfl_down(sz, off);
    }
    if (lane == 0) { wsum[0][wave] = sx; wsum[1][wave] = sy; wsum[2][wave] = sz; }
    __syncthreads();
    if (t == 0) {
        part[((size_t)b * 32 + sub) * 4 + 0] = wsum[0][0] + wsum[0][1] + wsum[0][2] + wsum[0][3];
        part[((size_t)b * 32 + sub) * 4 + 1] = wsum[1][0] + wsum[1][1] + wsum[1][2] + wsum[1][3];
        part[((size_t)b * 32 + sub) * 4 + 2] = wsum[2][0] + wsum[2][1] + wsum[2][2] + wsum[2][3];
    }
    grid.sync();

    // ---- P2: every block reduces its batch's 32 partials; then partial max ----
    double px = 0.0, py = 0.0, pz = 0.0;
    if (t < 32) {
        px = part[((size_t)b * 32 + t) * 4 + 0];
        py = part[((size_t)b * 32 + t) * 4 + 1];
        pz = part[((size_t)b * 32 + t) * 4 + 2];
    }
    if (t < 64) {
        for (int off = 16; off > 0; off >>= 1) {
            px += __shfl_down(px, off);
            py += __shfl_down(py, off);
            pz += __shfl_down(pz, off);
        }
        if (t == 0) {
            bshare[0] = (float)(px * (1.0 / NPTS));
            bshare[1] = (float)(py * (1.0 / NPTS));
            bshare[2] = (float)(pz * (1.0 / NPTS));
        }
    }
    __syncthreads();
    float mx = bshare[0], my = bshare[1], mz = bshare[2];

    float m = 0.0f;
#pragma unroll
    for (int j = 0; j < 8; j++) {
        int n = base + j * 256;
        float dx = cb[n] - mx;
        float dy = cb[NPTS + n] - my;
        float dz = cb[2 * NPTS + n] - mz;
        m = fmaxf(m, dx * dx + dy * dy + dz * dz);
    }
    for (int off = 32; off > 0; off >>= 1) m = fmaxf(m, __shfl_down(m, off));
    if (lane == 0) wmax[wave] = m;
    __syncthreads();
    if (t == 0) partmax[b * 32 + sub] = fmaxf(fmaxf(wmax[0], wmax[1]), fmaxf(wmax[2], wmax[3]));
    grid.sync();

    // ---- P3: reduce partmax -> denom; quantize, write nc/vid, histogram ----
    float pm = (t < 32) ? partmax[b * 32 + t] : 0.0f;
    if (t < 64) {
        for (int off = 16; off > 0; off >>= 1) pm = fmaxf(pm, __shfl_down(pm, off));
        if (t == 0) bshare[3] = 2.0f * sqrtf(pm);   // EPS = 0
    }
    __syncthreads();
    float denom = bshare[3];
    float* nb_ = ncout + (size_t)b * 3 * NPTS;
#pragma unroll
    for (int j = 0; j < 8; j++) {
        int n = base + j * 256;
        float dx = cb[n] - mx;
        float dy = cb[NPTS + n] - my;
        float dz = cb[2 * NPTS + n] - mz;
        float qx = fminf(fmaxf((dx / denom + 0.5f) * 32.0f, 0.0f), 31.0f);
        float qy = fminf(fmaxf((dy / denom + 0.5f) * 32.0f, 0.0f), 31.0f);
        float qz = fminf(fmaxf((dz / denom + 0.5f) * 32.0f, 0.0f), 31.0f);
        __builtin_nontemporal_store(qx, &nb_[n]);
        __builtin_nontemporal_store(qy, &nb_[NPTS + n]);
        __builtin_nontemporal_store(qz, &nb_[2 * NPTS + n]);
        int flat = ((int)rintf(qx) * RR + (int)rintf(qy)) * RR + (int)rintf(qz);
        vid[b * NPTS + n] = flat;
        atomicAdd(&cnt[b * R3 + flat], 1u);
    }
}

// ---------------- sorted pipeline ----------------

// Per-batch exclusive prefix over R3 voxels -> cursor. 1 block/batch.
__global__ void scan_kernel(const unsigned* __restrict__ cnt,
                            unsigned* __restrict__ cursor) {
    __shared__ unsigned ls[1024];
    int b = blockIdx.x;
    int t = threadIdx.x;
    const unsigned* c = cnt + b * R3;
    int base = t * 32;
    unsigned v[32];
    unsigned s = 0;
#pragma unroll
    for (int k = 0; k < 32; k++) {
        unsigned x = c[base + k];
        v[k] = s;
        s += x;
    }
    ls[t] = s;
    __syncthreads();
    for (int d = 1; d < 1024; d <<= 1) {
        unsigned x = (t >= d) ? ls[t - d] : 0u;
        __syncthreads();
        ls[t] += x;
        __syncthreads();
    }
    unsigned chunk_excl = (t == 0) ? 0u : ls[t - 1];
#pragma unroll
    for (int k = 0; k < 32; k++) {
        cursor[b * R3 + base + k] = chunk_excl + v[k];
    }
}

// Transpose 64x64 feature tile AND scatter rows to sorted positions (fp16).
__global__ void permute_kernel(const float* __restrict__ feats,
                               const int* __restrict__ vid,
                               unsigned* __restrict__ cursor,
                               __half* __restrict__ ft,
                               int* __restrict__ vid_sorted) {
    __shared__ float tile[64][65];
    __shared__ int spos[64];
    int b  = blockIdx.y;
    int n0 = blockIdx.x * 64;
    int t  = threadIdx.x;

    if (t < 64) {
        int flat = vid[b * NPTS + n0 + t];
        int pos = (int)atomicAdd(&cursor[b * R3 + flat], 1u);
        spos[t] = pos;
        vid_sorted[b * NPTS + pos] = flat;
    }

    const float* fb = feats + (size_t)b * NCH * NPTS + n0;
    int i  = t & 63;
    int c0 = t >> 6;
#pragma unroll
    for (int iter = 0; iter < 16; iter++) {
        int c = iter * 4 + c0;
        tile[i][c] = fb[(size_t)c * NPTS + i];
    }
    __syncthreads();

    int wave = t >> 6;
    int lane = t & 63;
    __half* fbase = ft + (size_t)b * NPTS * NCH + lane;
#pragma unroll
    for (int k = 0; k < 16; k++) {
        int p = wave * 16 + k;
        fbase[(size_t)spos[p] * NCH] = __float2half(tile[p][lane]);
    }
}

// Balanced segmented sum, half2-vectorized: each wave owns 64 consecutive
// sorted positions; half-wave h (32 lanes x 2 channels) processes points
// p0+2k+h. Sorted order => vid[p+2]==vid[p] iff positions p..p+2 share a voxel.
__global__ void segsum_kernel(const __half* __restrict__ ft,
                              const int* __restrict__ vid_sorted,
                              float* __restrict__ ws_vox) {
    __shared__ int svid[256];
    int b    = blockIdx.y;
    int t    = threadIdx.x;
    int wave = t >> 6;
    int lane = t & 63;
    int p0   = (blockIdx.x * 4 + wave) * 64;

    svid[t] = vid_sorted[b * NPTS + p0 + lane];   // per-wave slice

    int half = lane >> 5;
    int cl   = lane & 31;
    const __half2* fb2 = (const __half2*)(ft + ((size_t)b * NPTS + p0) * NCH);
    float* wv = ws_vox + (size_t)b * R3 * NCH;

    float s0 = 0.0f, s1 = 0.0f;
    int vcur = svid[wave * 64 + half];
#pragma unroll
    for (int k = 0; k < 32; k++) {
        int q = 2 * k + half;
        float2 f2 = __half22float2(fb2[q * 32 + cl]);
        s0 += f2.x;
        s1 += f2.y;
        int vnext = (k < 31) ? svid[wave * 64 + q + 2] : -1;
        if (vnext != vcur) {
            atomicAdd(wv + (size_t)vcur * NCH + 2 * cl, s0);
            atomicAdd(wv + (size_t)vcur * NCH + 2 * cl + 1, s1);
            s0 = 0.0f;
            s1 = 0.0f;
            vcur = vnext;
        }
    }
}

// ws_vox [B][R3][C] -> voxout [B][C][R3], divide by count, skip empty voxels.
__global__ void normalize_t_kernel(const float* __restrict__ ws_vox,
                                   const unsigned* __restrict__ cnt,
                                   float* __restrict__ voxout) {
    __shared__ float tile[64][65];
    __shared__ float cinv[64];
    __shared__ unsigned scnt[64];
    int b  = blockIdx.y;
    int v0 = blockIdx.x * 64;
    int t  = threadIdx.x;
    if (t < 64) {
        unsigned c = cnt[b * R3 + v0 + t];
        scnt[t] = c;
        cinv[t] = 1.0f / fmaxf((float)c, 1.0f);
    }
    __syncthreads();
    const float* src = ws_vox + ((size_t)b * R3 + v0) * NCH;
    int c = t & 63;
    int w = t >> 6;
#pragma unroll
    for (int iter = 0; iter < 16; iter++) {
        int vi = iter * 4 + w;
        tile[c][vi] = scnt[vi] ? src[(size_t)vi * NCH + c] * cinv[vi] : 0.0f;
    }
    __syncthreads();
    float* dst = voxout + (size_t)b * NCH * R3 + v0;
    int vi = t & 63;
#pragma unroll
    for (int iter = 0; iter < 16; iter++) {
        int cc = iter * 4 + w;
        __builtin_nontemporal_store(tile[cc][vi], &dst[(size_t)cc * R3 + vi]);
    }
}

extern "C" void kernel_launch(void* const* d_in, const int* in_sizes, int n_in,
                              void* d_out, int out_size, void* d_ws, size_t ws_size,
                              hipStream_t stream) {
    const float* feats  = (const float*)d_in[0];   // [8,64,65536]
    const float* coords = (const float*)d_in[1];   // [8,3,65536]
    float* out = (float*)d_out;
    float* voxout = out;                                   // [8,64,32768]
    float* ncout  = out + (size_t)NB * NCH * R3;           // [8,3,65536]

    // small scratch (plain-written before read; no zeroing needed)
    double* part    = (double*)d_ws;                       // [NB*32*4] = 8 KB
    float*  partmax = (float*)((char*)d_ws + 8192);        // [NB*32]   = 1 KB

    // zeroed region: cnt + ws_vox (contiguous)
    const size_t off_cnt   = 16384;
    const size_t cnt_bytes = (size_t)NB * R3 * 4;               // 1 MB
    const size_t off_vox   = off_cnt + cnt_bytes;
    const size_t vox_bytes = (size_t)NB * R3 * NCH * 4;         // 64 MB
    // non-zeroed big scratch
    const size_t off_cur   = off_vox + vox_bytes;
    const size_t off_vid   = off_cur + cnt_bytes;
    const size_t vid_bytes = (size_t)NB * NPTS * 4;             // 2 MB
    const size_t off_vs    = off_vid + vid_bytes;
    const size_t off_ft    = off_vs + vid_bytes;
    const size_t ft_bytes  = (size_t)NB * NPTS * NCH * 2;       // 64 MB fp16
    const size_t need_sort = off_ft + ft_bytes;                 // ~135 MB

    if (ws_size < need_sort) return;   // ws is ~512 MB in this harness; never taken

    unsigned* cnt    = (unsigned*)((char*)d_ws + off_cnt);
    float*    ws_vox = (float*)((char*)d_ws + off_vox);
    unsigned* cursor = (unsigned*)((char*)d_ws + off_cur);
    int*      vid    = (int*)((char*)d_ws + off_vid);
    int*      vid_s  = (int*)((char*)d_ws + off_vs);
    __half*   ft     = (__half*)((char*)d_ws + off_ft);

    hipMemsetAsync((char*)d_ws + off_cnt, 0, cnt_bytes + vox_bytes, stream);

    void* args[] = {(void*)&coords, (void*)&ncout, (void*)&vid, (void*)&cnt,
                    (void*)&part, (void*)&partmax};
    hipLaunchCooperativeKernel((const void*)prep_kernel, dim3(256), dim3(256),
                               args, 0, stream);

    scan_kernel   <<<NB, 1024, 0, stream>>>(cnt, cursor);
    permute_kernel<<<dim3(NPTS / 64, NB), 256, 0, stream>>>(feats, vid, cursor, ft, vid_s);
    segsum_kernel <<<dim3(NPTS / 256, NB), 256, 0, stream>>>(ft, vid_s, ws_vox);
    normalize_t_kernel<<<dim3(R3 / 64, NB), 256, 0, stream>>>(ws_vox, cnt, voxout);
}